// Round 1
// baseline (1626.467 us; speedup 1.0000x reference)
//
#include <hip/hip_runtime.h>
#include <hip/hip_fp16.h>
#include <cstdint>
#include <cstddef>

#define TTOK 8192
#define HD   2048
#define ID   4096
#define NE   8
#define NPAIR (TTOK * 2)            // 16384 routed pairs, fixed
#define PADMAX (NPAIR + NE * 128)   // 17408 worst-case padded rows

typedef _Float16 h8 __attribute__((ext_vector_type(8)));
typedef _Float16 h4 __attribute__((ext_vector_type(4)));
typedef float    f4 __attribute__((ext_vector_type(4)));

__device__ __forceinline__ void async_cp16(const void* g, void* l) {
  __builtin_amdgcn_global_load_lds(
      (const __attribute__((address_space(1))) unsigned int*)g,
      (__attribute__((address_space(3))) unsigned int*)l, 16, 0, 0);
}

__device__ __forceinline__ f4 zero4() { f4 z = {0.f, 0.f, 0.f, 0.f}; return z; }

// ---------------- fp32 -> f16 convert (vectorized, grid-stride) ----------------
__global__ void cvt_kernel(const float* __restrict__ src, _Float16* __restrict__ dst, size_t n) {
  size_t stride = (size_t)gridDim.x * blockDim.x * 8;
  for (size_t i = ((size_t)blockIdx.x * blockDim.x + threadIdx.x) * 8; i < n; i += stride) {
    const float4* s = (const float4*)(src + i);
    float4 a = s[0], b = s[1];
    h8 o;
    o[0] = (_Float16)a.x; o[1] = (_Float16)a.y; o[2] = (_Float16)a.z; o[3] = (_Float16)a.w;
    o[4] = (_Float16)b.x; o[5] = (_Float16)b.y; o[6] = (_Float16)b.z; o[7] = (_Float16)b.w;
    *(h8*)(dst + i) = o;
  }
}

// ---------------- gate: wave per token, 8 dots, top-2 ----------------
__global__ __launch_bounds__(256) void gate_kernel(
    const float* __restrict__ x, const float* __restrict__ gw,
    int* __restrict__ counts, int* __restrict__ tids, float* __restrict__ tw) {
  int lane = threadIdx.x & 63;
  int t = blockIdx.x * 4 + (threadIdx.x >> 6);
  const float* xr = x + (size_t)t * HD;
  float acc[NE];
#pragma unroll
  for (int e = 0; e < NE; e++) acc[e] = 0.f;
  for (int j = lane; j < HD; j += 64) {
    float xv = xr[j];
#pragma unroll
    for (int e = 0; e < NE; e++) acc[e] += xv * gw[e * HD + j];
  }
#pragma unroll
  for (int off = 32; off > 0; off >>= 1) {
#pragma unroll
    for (int e = 0; e < NE; e++) acc[e] += __shfl_xor(acc[e], off, 64);
  }
  if (lane == 0) {
    int e0 = 0; float v0 = acc[0];
#pragma unroll
    for (int e = 1; e < NE; e++) if (acc[e] > v0) { v0 = acc[e]; e0 = e; }
    int e1 = -1; float v1 = -1e30f;
#pragma unroll
    for (int e = 0; e < NE; e++) if (e != e0 && acc[e] > v1) { v1 = acc[e]; e1 = e; }
    // top-2 softmax weights: global softmax denominator cancels on renormalize
    float b = __expf(v1 - v0);
    float w0 = 1.f / (1.f + b);
    tids[2 * t] = e0; tids[2 * t + 1] = e1;
    tw[2 * t] = w0;   tw[2 * t + 1] = b * w0;
    atomicAdd(&counts[e0], 1); atomicAdd(&counts[e1], 1);
  }
}

// ---------------- scan: per-expert padded offsets ----------------
__global__ void scan_kernel(const int* __restrict__ counts, int* __restrict__ offs,
                            int* __restrict__ cursor) {
  if (threadIdx.x == 0 && blockIdx.x == 0) {
    int off = 0;
    for (int e = 0; e < NE; e++) {
      offs[e] = off; cursor[e] = off;
      off += ((counts[e] + 127) >> 7) << 7;
    }
    offs[NE] = off;
  }
}

// ---------------- scatter tokens into routed lists ----------------
__global__ void scatter_kernel(const int* __restrict__ tids, const float* __restrict__ tw,
                               int* __restrict__ cursor, int* __restrict__ perm,
                               float* __restrict__ pw) {
  int t = blockIdx.x * 256 + threadIdx.x;
#pragma unroll
  for (int k = 0; k < 2; k++) {
    int e = tids[2 * t + k];
    int pos = atomicAdd(&cursor[e], 1);
    perm[pos] = t; pw[pos] = tw[2 * t + k];
  }
}

// ---------------- mark padding slots ----------------
__global__ void padfill_kernel(const int* __restrict__ counts, const int* __restrict__ offs,
                               int* __restrict__ perm) {
  int s = blockIdx.x * 256 + threadIdx.x;
#pragma unroll
  for (int e = 0; e < NE; e++) {
    if (s >= offs[e] + counts[e] && s < offs[e + 1]) perm[s] = -1;
  }
}

// ---------------- gemm1: h = silu(x @ Wg^T) * (x @ Wu^T), routed rows ----------------
// 128x128 tile (x2: g and u halves), BK=32, 4 waves, 16x16x32 f16 MFMA
template <bool WPRE>
__global__ __launch_bounds__(256, 2) void gemm1_kernel(
    const _Float16* __restrict__ xh, const float* __restrict__ wsf,
    const _Float16* __restrict__ wsh,
    const int* __restrict__ counts, const int* __restrict__ offs,
    const int* __restrict__ perm, _Float16* __restrict__ hbuf) {
  int e = blockIdx.y >> 6, rb = blockIdx.y & 63;
  if (rb >= ((counts[e] + 127) >> 7)) return;
  int row0 = offs[e] + (rb << 7);
  int n0 = blockIdx.x << 7;  // over I (g half); u half at ID + n0

  __shared__ _Float16 As[128 * 32];
  __shared__ _Float16 Bg[128 * 32];
  __shared__ _Float16 Bu[128 * 32];
  int tid = threadIdx.x, lane = tid & 63, wid = tid >> 6, wr = wid >> 1, wc = wid & 1;

  const _Float16* asrc[2];
#pragma unroll
  for (int i = 0; i < 2; i++) {
    int slot = i * 256 + tid, r = slot >> 2, seg = slot & 3;
    int p = perm[row0 + r]; if (p < 0) p = 0;
    asrc[i] = xh + (size_t)p * HD + seg * 8;
  }
  const _Float16* bsg[2]; const _Float16* bsu[2];
  const float* fsg = nullptr; const float* fsu = nullptr;
  if constexpr (WPRE) {
#pragma unroll
    for (int i = 0; i < 2; i++) {
      int slot = i * 256 + tid, r = slot >> 2, seg = slot & 3;
      bsg[i] = wsh + ((size_t)e * 2 * ID + n0 + r) * HD + seg * 8;
      bsu[i] = wsh + ((size_t)e * 2 * ID + ID + n0 + r) * HD + seg * 8;
    }
  } else {
    int tr = tid >> 1, hf = tid & 1;
    fsg = wsf + ((size_t)e * 2 * ID + n0 + tr) * HD + hf * 16;
    fsu = wsf + ((size_t)e * 2 * ID + ID + n0 + tr) * HD + hf * 16;
  }

  auto stage = [&](int kt) {
    int kof = kt * 32;
#pragma unroll
    for (int i = 0; i < 2; i++) async_cp16(asrc[i] + kof, &As[(i * 256 + tid) * 8]);
    if constexpr (WPRE) {
#pragma unroll
      for (int i = 0; i < 2; i++) {
        async_cp16(bsg[i] + kof, &Bg[(i * 256 + tid) * 8]);
        async_cp16(bsu[i] + kof, &Bu[(i * 256 + tid) * 8]);
      }
    } else {
      int tr = tid >> 1, hf = tid & 1;
#pragma unroll
      for (int j = 0; j < 4; j++) {
        float4 vg = *(const float4*)(fsg + kof + j * 4);
        float4 vu = *(const float4*)(fsu + kof + j * 4);
        h4 og, ou;
        og[0] = (_Float16)vg.x; og[1] = (_Float16)vg.y; og[2] = (_Float16)vg.z; og[3] = (_Float16)vg.w;
        ou[0] = (_Float16)vu.x; ou[1] = (_Float16)vu.y; ou[2] = (_Float16)vu.z; ou[3] = (_Float16)vu.w;
        *(h4*)&Bg[tr * 32 + hf * 16 + j * 4] = og;
        *(h4*)&Bu[tr * 32 + hf * 16 + j * 4] = ou;
      }
    }
  };

  f4 accg[4][4], accu[4][4];
#pragma unroll
  for (int m = 0; m < 4; m++)
#pragma unroll
    for (int n = 0; n < 4; n++) { accg[m][n] = zero4(); accu[m][n] = zero4(); }

  stage(0);
  const int NK = HD / 32;  // 64
  for (int kt = 0; kt < NK; ++kt) {
    __syncthreads();
    int lr = lane & 15, ks = lane >> 4;
    h8 af[4], bg[4], bu[4];
#pragma unroll
    for (int m = 0; m < 4; m++)
      af[m] = *(const h8*)&As[((wr << 6) + (m << 4) + lr) * 32 + ks * 8];
#pragma unroll
    for (int n = 0; n < 4; n++) {
      bg[n] = *(const h8*)&Bg[((wc << 6) + (n << 4) + lr) * 32 + ks * 8];
      bu[n] = *(const h8*)&Bu[((wc << 6) + (n << 4) + lr) * 32 + ks * 8];
    }
#pragma unroll
    for (int m = 0; m < 4; m++)
#pragma unroll
      for (int n = 0; n < 4; n++) {
        accg[m][n] = __builtin_amdgcn_mfma_f32_16x16x32_f16(af[m], bg[n], accg[m][n], 0, 0, 0);
        accu[m][n] = __builtin_amdgcn_mfma_f32_16x16x32_f16(af[m], bu[n], accu[m][n], 0, 0, 0);
      }
    __syncthreads();
    if (kt + 1 < NK) stage(kt + 1);
  }

  int lr = lane & 15, lg = lane >> 4;
#pragma unroll
  for (int m = 0; m < 4; m++)
#pragma unroll
    for (int n = 0; n < 4; n++)
#pragma unroll
      for (int r = 0; r < 4; r++) {
        int grow = (wr << 6) + (m << 4) + (lg << 2) + r;
        int gcol = n0 + (wc << 6) + (n << 4) + lr;
        float g = accg[m][n][r], u = accu[m][n][r];
        float hv = g / (1.f + __expf(-g)) * u;
        hbuf[(size_t)(row0 + grow) * ID + gcol] = (_Float16)hv;
      }
}

// ---------------- gemm2: out[t] += w * (h @ W2^T), scatter-add ----------------
template <bool WPRE>
__global__ __launch_bounds__(256, 2) void gemm2_kernel(
    const _Float16* __restrict__ hbuf, const float* __restrict__ w2f,
    const _Float16* __restrict__ w2h,
    const int* __restrict__ counts, const int* __restrict__ offs,
    const int* __restrict__ perm, const float* __restrict__ pw,
    float* __restrict__ out) {
  int e = blockIdx.y >> 6, rb = blockIdx.y & 63;
  if (rb >= ((counts[e] + 127) >> 7)) return;
  int row0 = offs[e] + (rb << 7);
  int n0 = blockIdx.x << 7;  // over H: grid.x = 16

  __shared__ _Float16 As[128 * 32];
  __shared__ _Float16 Bs[128 * 32];
  int tid = threadIdx.x, lane = tid & 63, wid = tid >> 6, wr = wid >> 1, wc = wid & 1;

  const _Float16* asrc[2]; const _Float16* bs[2]; const float* fs = nullptr;
#pragma unroll
  for (int i = 0; i < 2; i++) {
    int slot = i * 256 + tid, r = slot >> 2, seg = slot & 3;
    asrc[i] = hbuf + (size_t)(row0 + r) * ID + seg * 8;
    if constexpr (WPRE) bs[i] = w2h + ((size_t)e * HD + n0 + r) * ID + seg * 8;
  }
  if constexpr (!WPRE) {
    int tr = tid >> 1, hf = tid & 1;
    fs = w2f + ((size_t)e * HD + n0 + tr) * ID + hf * 16;
  }

  auto stage = [&](int kt) {
    int kof = kt * 32;
#pragma unroll
    for (int i = 0; i < 2; i++) async_cp16(asrc[i] + kof, &As[(i * 256 + tid) * 8]);
    if constexpr (WPRE) {
#pragma unroll
      for (int i = 0; i < 2; i++) async_cp16(bs[i] + kof, &Bs[(i * 256 + tid) * 8]);
    } else {
      int tr = tid >> 1, hf = tid & 1;
#pragma unroll
      for (int j = 0; j < 4; j++) {
        float4 v = *(const float4*)(fs + kof + j * 4);
        h4 o;
        o[0] = (_Float16)v.x; o[1] = (_Float16)v.y; o[2] = (_Float16)v.z; o[3] = (_Float16)v.w;
        *(h4*)&Bs[tr * 32 + hf * 16 + j * 4] = o;
      }
    }
  };

  f4 acc[4][4];
#pragma unroll
  for (int m = 0; m < 4; m++)
#pragma unroll
    for (int n = 0; n < 4; n++) acc[m][n] = zero4();

  stage(0);
  const int NK = ID / 32;  // 128
  for (int kt = 0; kt < NK; ++kt) {
    __syncthreads();
    int lr = lane & 15, ks = lane >> 4;
    h8 af[4], bf[4];
#pragma unroll
    for (int m = 0; m < 4; m++)
      af[m] = *(const h8*)&As[((wr << 6) + (m << 4) + lr) * 32 + ks * 8];
#pragma unroll
    for (int n = 0; n < 4; n++)
      bf[n] = *(const h8*)&Bs[((wc << 6) + (n << 4) + lr) * 32 + ks * 8];
#pragma unroll
    for (int m = 0; m < 4; m++)
#pragma unroll
      for (int n = 0; n < 4; n++)
        acc[m][n] = __builtin_amdgcn_mfma_f32_16x16x32_f16(af[m], bf[n], acc[m][n], 0, 0, 0);
    __syncthreads();
    if (kt + 1 < NK) stage(kt + 1);
  }

  int lr = lane & 15, lg = lane >> 4;
#pragma unroll
  for (int m = 0; m < 4; m++)
#pragma unroll
    for (int r = 0; r < 4; r++) {
      int row = row0 + (wr << 6) + (m << 4) + (lg << 2) + r;
      int t = perm[row];
      if (t < 0) continue;
      float w = pw[row];
#pragma unroll
      for (int n = 0; n < 4; n++) {
        int gcol = n0 + (wc << 6) + (n << 4) + lr;
        atomicAdd(&out[(size_t)t * HD + gcol], acc[m][n][r] * w);
      }
    }
}

// ---------------- host launcher ----------------
extern "C" void kernel_launch(void* const* d_in, const int* in_sizes, int n_in,
                              void* d_out, int out_size, void* d_ws, size_t ws_size,
                              hipStream_t stream) {
  const float* x   = (const float*)d_in[0];
  const float* gw  = (const float*)d_in[1];
  const float* wsf = (const float*)d_in[2];
  const float* w2f = (const float*)d_in[3];

  // ---- workspace layout ----
  int* counts  = (int*)d_ws;           // 8
  int* offs    = counts + 8;           // 9 (16 reserved)
  int* cursor  = offs + 16;            // 8
  int* tids    = cursor + 8;           // 2*T
  float* tw    = (float*)(tids + NPAIR);
  int* perm    = (int*)(tw + NPAIR);   // PADMAX
  float* pw    = (float*)(perm + PADMAX);

  char* base = (char*)d_ws;
  size_t off_xh = (size_t)512 * 1024;
  size_t off_h  = off_xh + (size_t)TTOK * HD * 2;
  size_t base_end = off_h + (size_t)PADMAX * ID * 2;   // ~169 MB
  if (ws_size < base_end) return;  // workspace too small: clean bail (absmax 2.67 signature)

  _Float16* xh = (_Float16*)(base + off_xh);
  _Float16* hb = (_Float16*)(base + off_h);

  size_t nws = (size_t)NE * 2 * ID * HD;  // 134,217,728
  size_t nw2 = (size_t)NE * HD * ID;      //  67,108,864
  bool wpre = (ws_size >= base_end + (nws + nw2) * 2);
  _Float16* wsh = nullptr; _Float16* w2h = nullptr;
  if (wpre) { wsh = (_Float16*)(base + base_end); w2h = wsh + nws; }

  hipMemsetAsync(counts, 0, 64, stream);
  hipMemsetAsync(d_out, 0, (size_t)out_size * 4, stream);

  cvt_kernel<<<2048, 256, 0, stream>>>(x, xh, (size_t)TTOK * HD);
  if (wpre) {
    cvt_kernel<<<4096, 256, 0, stream>>>(wsf, wsh, nws);
    cvt_kernel<<<4096, 256, 0, stream>>>(w2f, w2h, nw2);
  }
  gate_kernel<<<TTOK / 4, 256, 0, stream>>>(x, gw, counts, tids, tw);
  scan_kernel<<<1, 64, 0, stream>>>(counts, offs, cursor);
  scatter_kernel<<<TTOK / 256, 256, 0, stream>>>(tids, tw, cursor, perm, pw);
  padfill_kernel<<<PADMAX / 256, 256, 0, stream>>>(counts, offs, perm);

  dim3 g1(ID / 128, NE * (TTOK / 128));   // 32 x 512
  dim3 g2(HD / 128, NE * (TTOK / 128));   // 16 x 512
  if (wpre) {
    gemm1_kernel<true><<<g1, 256, 0, stream>>>(xh, wsf, wsh, counts, offs, perm, hb);
    gemm2_kernel<true><<<g2, 256, 0, stream>>>(hb, w2f, w2h, counts, offs, perm, pw, (float*)d_out);
  } else {
    gemm1_kernel<false><<<g1, 256, 0, stream>>>(xh, wsf, wsh, counts, offs, perm, hb);
    gemm2_kernel<false><<<g2, 256, 0, stream>>>(hb, w2f, w2h, counts, offs, perm, pw, (float*)d_out);
  }
}